// Round 8
// baseline (1800.762 us; speedup 1.0000x reference)
//
#include <hip/hip_runtime.h>
#include <hip/hip_fp16.h>

#define NN 50000
#define NR 4
#define NE 800000
#define DD 128
#define NSEG (NR * NN)                       // 200000 segments
#define SCHUNK 1024
#define NCHUNK ((NSEG + SCHUNK - 1) / SCHUNK)  // 196

// hetero geometry: 512 m-blocks (128/rel, 391 nodes each) interleaved
// every 25th blockIdx among 12500 place-blocks (256 edges each).
#define NBM 512
#define MSTRIDE 25
#define NODES_PER_MBLK 391   // 128 * 391 = 50048 >= NN

// ---------------------------------------------------------------------------
// count: cnt[r*NN + dst]++ over all 3.2M edges
// ---------------------------------------------------------------------------
__global__ __launch_bounds__(256) void count_kernel(
    const int* __restrict__ eidx, int* __restrict__ cnt) {
  int idx = blockIdx.x * 256 + threadIdx.x;
  if (idx >= NR * NE) return;
  int r = idx / NE, e = idx - r * NE;
  int dst = eidx[(size_t)r * 2 * NE + NE + e];
  atomicAdd(&cnt[r * NN + dst], 1);
}

// ---------------------------------------------------------------------------
// 3-kernel exclusive scan over cnt[NSEG] -> off[NSEG]; off_run = copy
// ---------------------------------------------------------------------------
__global__ __launch_bounds__(256) void scan_local(
    const int* __restrict__ cnt, int* __restrict__ off,
    int* __restrict__ partial) {
  __shared__ int lds[256];
  int base = blockIdx.x * SCHUNK, t = threadIdx.x;
  int v[4], s = 0;
#pragma unroll
  for (int j = 0; j < 4; ++j) {
    int i = base + t * 4 + j;
    v[j] = (i < NSEG) ? cnt[i] : 0;
    s += v[j];
  }
  lds[t] = s;
  __syncthreads();
  for (int d = 1; d < 256; d <<= 1) {
    int x = (t >= d) ? lds[t - d] : 0;
    __syncthreads();
    lds[t] += x;
    __syncthreads();
  }
  int excl = (t == 0) ? 0 : lds[t - 1];
  if (t == 255) partial[blockIdx.x] = lds[255];
#pragma unroll
  for (int j = 0; j < 4; ++j) {
    int i = base + t * 4 + j;
    if (i < NSEG) off[i] = excl;
    excl += v[j];
  }
}

__global__ __launch_bounds__(256) void scan_partials(int* __restrict__ partial) {
  __shared__ int lds[256];
  int t = threadIdx.x;
  int v = (t < NCHUNK) ? partial[t] : 0;
  lds[t] = v;
  __syncthreads();
  for (int d = 1; d < 256; d <<= 1) {
    int x = (t >= d) ? lds[t - d] : 0;
    __syncthreads();
    lds[t] += x;
    __syncthreads();
  }
  int excl = (t == 0) ? 0 : lds[t - 1];
  if (t < NCHUNK) partial[t] = excl;
}

__global__ __launch_bounds__(256) void scan_add(
    int* __restrict__ off, const int* __restrict__ partial,
    int* __restrict__ off_run) {
  int base = blockIdx.x * SCHUNK;
  int add = partial[blockIdx.x];
  for (int j = threadIdx.x; j < SCHUNK; j += 256) {
    int i = base + j;
    if (i < NSEG) {
      int o = off[i] + add;
      off[i] = o;
      off_run[i] = o;
    }
  }
}

// ---------------------------------------------------------------------------
// HETERO place + M: independent work overlapped in one launch.
//  place path (12500 blocks): s_rec[pos] = (src,w), pos = off_run[seg]++.
//    latency/ownership-bound, ~10 VGPR, waves mostly idle -> VALU free.
//  m path (512 blocks): M_r = F @ Wr[r] in fp16, W held in REGISTERS
//    (no LDS so place occupancy is unharmed). wave = 8 kg-groups x 8 cols;
//    lane owns W[16k x 1 col] slice (16 VGPR); kg-reduce via shfl_xor.
//    4 col-passes x 391 nodes per block.
// __launch_bounds__(256,8): cap 64 VGPR so 32 waves/CU stay resident.
// ---------------------------------------------------------------------------
__global__ __launch_bounds__(256, 8) void place_m_kernel(
    const int* __restrict__ eidx, const float* __restrict__ ew,
    int* __restrict__ off_run, int2* __restrict__ s_rec,
    const float* __restrict__ feat, const float* __restrict__ Wr,
    __half* __restrict__ M) {
  int bid = blockIdx.x;
  bool is_m = (bid % MSTRIDE == 0) && (bid / MSTRIDE < NBM);
  if (is_m) {
    int mid = bid / MSTRIDE;
    int r = mid >> 7;              // 128 blocks per relation
    int nb = mid & 127;
    int n0 = nb * NODES_PER_MBLK;
    int n1 = n0 + NODES_PER_MBLK;
    if (n1 > NN) n1 = NN;
    int wv = threadIdx.x >> 6, l = threadIdx.x & 63;
    int kg = l >> 3, cg = l & 7;
    const float* W = Wr + (size_t)r * DD * DD;
    __half* Mr = M + (size_t)r * NN * DD;
    for (int p = 0; p < 4; ++p) {
      int col = p * 32 + wv * 8 + cg;
      float wreg[16];
#pragma unroll
      for (int t = 0; t < 16; ++t) wreg[t] = W[(kg * 16 + t) * DD + col];
      for (int n = n0; n < n1; ++n) {
        const float4* fb =
            reinterpret_cast<const float4*>(feat + (size_t)n * DD + kg * 16);
        float4 f0 = fb[0], f1 = fb[1], f2 = fb[2], f3 = fb[3];
        float acc;
        acc  = f0.x * wreg[0]  + f0.y * wreg[1]  + f0.z * wreg[2]  + f0.w * wreg[3];
        acc += f1.x * wreg[4]  + f1.y * wreg[5]  + f1.z * wreg[6]  + f1.w * wreg[7];
        acc += f2.x * wreg[8]  + f2.y * wreg[9]  + f2.z * wreg[10] + f2.w * wreg[11];
        acc += f3.x * wreg[12] + f3.y * wreg[13] + f3.z * wreg[14] + f3.w * wreg[15];
        acc += __shfl_xor(acc, 8);
        acc += __shfl_xor(acc, 16);
        acc += __shfl_xor(acc, 32);
        if (kg == 0) Mr[(size_t)n * DD + col] = __float2half(acc);
      }
    }
  } else {
    int nm = bid / MSTRIDE + 1;
    if (nm > NBM) nm = NBM;
    int pid = bid - nm;            // place-block linear id in [0, 12500)
    int idx = pid * 256 + threadIdx.x;
    if (idx >= NR * NE) return;
    int r = idx / NE, e = idx - r * NE;
    int src = eidx[(size_t)r * 2 * NE + e];
    int dst = eidx[(size_t)r * 2 * NE + NE + e];
    float w = ew[(size_t)r * NE + e];
    int pos = atomicAdd(&off_run[r * NN + dst], 1);
    long long rec =
        (long long)(unsigned int)src | ((long long)__float_as_uint(w) << 32);
    __builtin_nontemporal_store(rec, reinterpret_cast<long long*>(s_rec + pos));
  }
}

// ---------------------------------------------------------------------------
// gather_y (with INLINE rel_w softmax): one wave per node, zero LDS.
// rel_w: butterfly-reduced dot over the wave (Wrw is 2KB, L1-hot).
// y[n] = sum_r rw[n,r] * ( sum_e w_e * M_r[src_e] + (sum_e w_e) * br[r] )
// Records streamed with nontemporal loads (read-once; keep M in L2).
// ---------------------------------------------------------------------------
__global__ __launch_bounds__(256) void gather_y(
    const __half* __restrict__ M, const int2* __restrict__ s_rec,
    const int* __restrict__ off, const int* __restrict__ cnt,
    const float* __restrict__ feat, const float* __restrict__ Wrw,
    const float* __restrict__ brw, const float* __restrict__ br,
    float* __restrict__ y) {
  int wave = threadIdx.x >> 6, lane = threadIdx.x & 63;
  int n = blockIdx.x * 4 + wave;
  if (n >= NN) return;

  // ---- inline rel_w softmax (all lanes end with rwv[0..3]) ----
  float rwv[4];
  {
    float2 f = reinterpret_cast<const float2*>(feat + (size_t)n * DD)[lane];
    float4 w0 = reinterpret_cast<const float4*>(Wrw)[2 * lane];
    float4 w1 = reinterpret_cast<const float4*>(Wrw)[2 * lane + 1];
    float a0 = f.x * w0.x + f.y * w1.x;
    float a1 = f.x * w0.y + f.y * w1.y;
    float a2 = f.x * w0.z + f.y * w1.z;
    float a3 = f.x * w0.w + f.y * w1.w;
    for (int o = 32; o; o >>= 1) {
      a0 += __shfl_xor(a0, o);
      a1 += __shfl_xor(a1, o);
      a2 += __shfl_xor(a2, o);
      a3 += __shfl_xor(a3, o);
    }
    a0 += brw[0]; a1 += brw[1]; a2 += brw[2]; a3 += brw[3];
    float m = fmaxf(fmaxf(a0, a1), fmaxf(a2, a3));
    float e0 = __expf(a0 - m), e1 = __expf(a1 - m);
    float e2 = __expf(a2 - m), e3 = __expf(a3 - m);
    float inv = 1.f / (e0 + e1 + e2 + e3);
    rwv[0] = e0 * inv; rwv[1] = e1 * inv; rwv[2] = e2 * inv; rwv[3] = e3 * inv;
  }

  float2 acc = make_float2(0.f, 0.f);
#pragma unroll
  for (int r = 0; r < NR; ++r) {
    int seg = r * NN + n;
    int start = off[seg], deg = cnt[seg];
    const __half2* mbase =
        reinterpret_cast<const __half2*>(M + (size_t)r * NN * DD);
    float2 pacc = make_float2(0.f, 0.f);
    float sw = 0.f;
    for (int i = 0; i < deg; i += 8) {
      int nb = deg - i;
      nb = nb > 8 ? 8 : nb;
      long long rr = 0;
      if (lane < nb)
        rr = __builtin_nontemporal_load(
            reinterpret_cast<const long long*>(s_rec + start + i + lane));
      int src_l = (int)(unsigned int)rr;
      float w_l = __uint_as_float((unsigned int)((unsigned long long)rr >> 32));
      if (nb == 8) {
#pragma unroll
        for (int j = 0; j < 8; ++j) {
          int s = __shfl(src_l, j);
          float w = __shfl(w_l, j);
          float2 mf = __half22float2(mbase[(size_t)s * 64 + lane]);
          pacc.x += w * mf.x;
          pacc.y += w * mf.y;
          sw += w;
        }
      } else {
        for (int j = 0; j < nb; ++j) {
          int s = __shfl(src_l, j);
          float w = __shfl(w_l, j);
          float2 mf = __half22float2(mbase[(size_t)s * 64 + lane]);
          pacc.x += w * mf.x;
          pacc.y += w * mf.y;
          sw += w;
        }
      }
    }
    float2 bv = reinterpret_cast<const float2*>(br + (size_t)r * DD)[lane];
    float rw = rwv[r];
    acc.x += rw * (pacc.x + sw * bv.x);
    acc.y += rw * (pacc.y + sw * bv.y);
  }
  reinterpret_cast<float2*>(y + (size_t)n * DD)[lane] = acc;
}

// ---------------------------------------------------------------------------
// gate: out = sigmoid(out @ Wg + bg) * out, in place. 128 nodes/block
// (16 sub-iters) so Wg staging is amortized 4x more than 32-node blocks.
// ---------------------------------------------------------------------------
__global__ __launch_bounds__(256) void gate_kernel(
    float* __restrict__ out, const float* __restrict__ Wg,
    const float* __restrict__ bg) {
  __shared__ float wlds[DD * DD];
  __shared__ float clds[8][DD];
  for (int i = threadIdx.x; i < DD * DD / 4; i += 256)
    reinterpret_cast<float4*>(wlds)[i] = reinterpret_cast<const float4*>(Wg)[i];
  int dgrp = threadIdx.x & 31, nl = threadIdx.x >> 5;
  float4 bv = reinterpret_cast<const float4*>(bg)[dgrp];
  int nbase = blockIdx.x * 128;
  for (int s = 0; s < 16; ++s) {
    int n0 = nbase + s * 8;
    __syncthreads();
    {
      int n = n0 + nl;
      float4 cv = make_float4(0.f, 0.f, 0.f, 0.f);
      if (n < NN) cv = reinterpret_cast<const float4*>(out + (size_t)n * DD)[dgrp];
      reinterpret_cast<float4*>(&clds[nl][0])[dgrp] = cv;
    }
    __syncthreads();
    int n = n0 + nl;
    float4 acc = bv;
#pragma unroll 8
    for (int k = 0; k < DD; ++k) {
      float c = clds[nl][k];
      float4 wv = reinterpret_cast<const float4*>(&wlds[k * DD])[dgrp];
      acc.x += c * wv.x; acc.y += c * wv.y;
      acc.z += c * wv.z; acc.w += c * wv.w;
    }
    if (n < NN) {
      float4 cv = reinterpret_cast<float4*>(&clds[nl][0])[dgrp];
      float4 res;
      res.x = cv.x / (1.f + __expf(-acc.x));
      res.y = cv.y / (1.f + __expf(-acc.y));
      res.z = cv.z / (1.f + __expf(-acc.z));
      res.w = cv.w / (1.f + __expf(-acc.w));
      reinterpret_cast<float4*>(out + (size_t)n * DD)[dgrp] = res;
    }
  }
}

// ---------------------------------------------------------------------------
extern "C" void kernel_launch(void* const* d_in, const int* in_sizes, int n_in,
                              void* d_out, int out_size, void* d_ws,
                              size_t ws_size, hipStream_t stream) {
  const float* feat = (const float*)d_in[0];
  const int* eidx   = (const int*)d_in[1];   // [4][2][800000] int32
  const float* ew   = (const float*)d_in[2];
  const float* Wr   = (const float*)d_in[3];
  const float* br   = (const float*)d_in[4];
  const float* Wrw  = (const float*)d_in[5];
  const float* brw  = (const float*)d_in[6];
  const float* Wg   = (const float*)d_in[7];
  const float* bg   = (const float*)d_in[8];
  float* out = (float*)d_out;

  // ws layout (~79 MB): s_rec | cnt | off | offrun | part | M
  char* p = (char*)d_ws;
  int2*   s_rec  = (int2*)p;   p += (size_t)NR * NE * 8;       // 25.6 MB
  int*    cnt    = (int*)p;    p += (size_t)NSEG * 4;
  int*    off    = (int*)p;    p += (size_t)NSEG * 4;
  int*    offrun = (int*)p;    p += (size_t)NSEG * 4;
  int*    part   = (int*)p;    p += 4096;
  __half* M      = (__half*)p; p += (size_t)NR * NN * DD * 2;  // 51.2 MB

  hipMemsetAsync(cnt, 0, (size_t)NSEG * 4, stream);

  count_kernel<<<(NR * NE + 255) / 256, 256, 0, stream>>>(eidx, cnt);
  scan_local<<<NCHUNK, 256, 0, stream>>>(cnt, off, part);
  scan_partials<<<1, 256, 0, stream>>>(part);
  scan_add<<<NCHUNK, 256, 0, stream>>>(off, part, offrun);

  // hetero: 12500 place-blocks + 512 m-blocks interleaved
  place_m_kernel<<<12500 + NBM, 256, 0, stream>>>(eidx, ew, offrun, s_rec,
                                                  feat, Wr, M);

  gather_y<<<(NN + 3) / 4, 256, 0, stream>>>(M, s_rec, off, cnt, feat, Wrw,
                                             brw, br, out);
  gate_kernel<<<(NN + 127) / 128, 256, 0, stream>>>(out, Wg, bg);
}

// Round 9
// 828.780 us; speedup vs baseline: 2.1728x; 2.1728x over previous
//
#include <hip/hip_runtime.h>
#include <hip/hip_fp16.h>

#define NN 50000
#define NR 4
#define NE 800000
#define DD 128
#define NSEG (NR * NN)                       // 200000 segments
#define SCHUNK 1024
#define NCHUNK ((NSEG + SCHUNK - 1) / SCHUNK)  // 196

// XCD slicing for count/place: 8 dst-slices, block bid&7 owns slice bid&7.
// All atomics+writes for a slice issue from one XCD -> L2-local ownership.
#define NXCD 8
#define DSLICE (NN / NXCD)      // 6250
#define CBLK 1563               // virtual blocks per slice; 8*1563 = 12504

// ---------------------------------------------------------------------------
// count (XCD-sliced): cnt[r*NN + dst]++ over all 3.2M edges
// ---------------------------------------------------------------------------
__global__ __launch_bounds__(256) void count_kernel(
    const int* __restrict__ eidx, int* __restrict__ cnt) {
  int xcd = blockIdx.x & (NXCD - 1);
  int vb = blockIdx.x >> 3;
  int lo = xcd * DSLICE, hi = lo + DSLICE;
  for (int idx = vb * 256 + threadIdx.x; idx < NR * NE; idx += CBLK * 256) {
    int r = idx / NE, e = idx - r * NE;
    int dst = eidx[(size_t)r * 2 * NE + NE + e];
    if (dst >= lo && dst < hi) atomicAdd(&cnt[r * NN + dst], 1);
  }
}

// ---------------------------------------------------------------------------
// 3-kernel exclusive scan over cnt[NSEG] -> off[NSEG]; off_run = copy
// ---------------------------------------------------------------------------
__global__ __launch_bounds__(256) void scan_local(
    const int* __restrict__ cnt, int* __restrict__ off,
    int* __restrict__ partial) {
  __shared__ int lds[256];
  int base = blockIdx.x * SCHUNK, t = threadIdx.x;
  int v[4], s = 0;
#pragma unroll
  for (int j = 0; j < 4; ++j) {
    int i = base + t * 4 + j;
    v[j] = (i < NSEG) ? cnt[i] : 0;
    s += v[j];
  }
  lds[t] = s;
  __syncthreads();
  for (int d = 1; d < 256; d <<= 1) {
    int x = (t >= d) ? lds[t - d] : 0;
    __syncthreads();
    lds[t] += x;
    __syncthreads();
  }
  int excl = (t == 0) ? 0 : lds[t - 1];
  if (t == 255) partial[blockIdx.x] = lds[255];
#pragma unroll
  for (int j = 0; j < 4; ++j) {
    int i = base + t * 4 + j;
    if (i < NSEG) off[i] = excl;
    excl += v[j];
  }
}

__global__ __launch_bounds__(256) void scan_partials(int* __restrict__ partial) {
  __shared__ int lds[256];
  int t = threadIdx.x;
  int v = (t < NCHUNK) ? partial[t] : 0;
  lds[t] = v;
  __syncthreads();
  for (int d = 1; d < 256; d <<= 1) {
    int x = (t >= d) ? lds[t - d] : 0;
    __syncthreads();
    lds[t] += x;
    __syncthreads();
  }
  int excl = (t == 0) ? 0 : lds[t - 1];
  if (t < NCHUNK) partial[t] = excl;
}

__global__ __launch_bounds__(256) void scan_add(
    int* __restrict__ off, const int* __restrict__ partial,
    int* __restrict__ off_run) {
  int base = blockIdx.x * SCHUNK;
  int add = partial[blockIdx.x];
  for (int j = threadIdx.x; j < SCHUNK; j += 256) {
    int i = base + j;
    if (i < NSEG) {
      int o = off[i] + add;
      off[i] = o;
      off_run[i] = o;
    }
  }
}

// ---------------------------------------------------------------------------
// place (XCD-sliced): s_rec[pos] = (src,w), pos = off_run[seg]++.
// Slice x's s_rec region (~3.2MB) and off_run region (~100KB) are touched
// only by XCD x -> line ownership stays in one L2. NT store: written once,
// read next kernel.
// ---------------------------------------------------------------------------
__global__ __launch_bounds__(256) void place_kernel(
    const int* __restrict__ eidx, const float* __restrict__ ew,
    int* __restrict__ off_run, int2* __restrict__ s_rec) {
  int xcd = blockIdx.x & (NXCD - 1);
  int vb = blockIdx.x >> 3;
  int lo = xcd * DSLICE, hi = lo + DSLICE;
  for (int idx = vb * 256 + threadIdx.x; idx < NR * NE; idx += CBLK * 256) {
    int r = idx / NE, e = idx - r * NE;
    int dst = eidx[(size_t)r * 2 * NE + NE + e];
    if (dst >= lo && dst < hi) {
      int src = eidx[(size_t)r * 2 * NE + e];
      float w = ew[(size_t)r * NE + e];
      int pos = atomicAdd(&off_run[r * NN + dst], 1);
      long long rec =
          (long long)(unsigned int)src | ((long long)__float_as_uint(w) << 32);
      __builtin_nontemporal_store(rec,
                                  reinterpret_cast<long long*>(s_rec + pos));
    }
  }
}

// ---------------------------------------------------------------------------
// m_kernel: M_r = F @ Wr[r] in fp16. blockIdx.y = r. 128 nodes/block
// (16 sub-iters of 8); Wr (64KB) in LDS, F rows staged (4KB).
// ---------------------------------------------------------------------------
__global__ __launch_bounds__(256) void m_kernel(
    const float* __restrict__ feat, const float* __restrict__ Wr,
    __half* __restrict__ M) {
  __shared__ float wlds[DD * DD];   // 64 KB
  __shared__ float flds[8][DD];     // 4 KB
  int r = blockIdx.y;
  const float* W = Wr + (size_t)r * DD * DD;
  for (int i = threadIdx.x; i < DD * DD / 4; i += 256)
    reinterpret_cast<float4*>(wlds)[i] = reinterpret_cast<const float4*>(W)[i];
  int dgrp = threadIdx.x & 31, nl = threadIdx.x >> 5;
  int nbase = blockIdx.x * 128;
  for (int s = 0; s < 16; ++s) {
    int n0 = nbase + s * 8;
    __syncthreads();
    {
      int n = n0 + nl;
      float4 fv = make_float4(0.f, 0.f, 0.f, 0.f);
      if (n < NN) fv = reinterpret_cast<const float4*>(feat + (size_t)n * DD)[dgrp];
      reinterpret_cast<float4*>(&flds[nl][0])[dgrp] = fv;
    }
    __syncthreads();
    int n = n0 + nl;
    float4 acc = make_float4(0.f, 0.f, 0.f, 0.f);
#pragma unroll 8
    for (int k = 0; k < DD; ++k) {
      float f = flds[nl][k];
      float4 wv = reinterpret_cast<const float4*>(&wlds[k * DD])[dgrp];
      acc.x += f * wv.x; acc.y += f * wv.y;
      acc.z += f * wv.z; acc.w += f * wv.w;
    }
    if (n < NN) {
      __half2 h01 = __floats2half2_rn(acc.x, acc.y);
      __half2 h23 = __floats2half2_rn(acc.z, acc.w);
      __half2* mp = reinterpret_cast<__half2*>(
          M + ((size_t)r * NN + n) * DD + 4 * dgrp);
      mp[0] = h01;
      mp[1] = h23;
    }
  }
}

// ---------------------------------------------------------------------------
// gather_y (with INLINE rel_w softmax): one wave per node, zero LDS.
// y[n] = sum_r rw[n,r] * ( sum_e w_e * M_r[src_e] + (sum_e w_e) * br[r] )
// Records streamed with nontemporal loads (read-once; keep M in L2).
// ---------------------------------------------------------------------------
__global__ __launch_bounds__(256) void gather_y(
    const __half* __restrict__ M, const int2* __restrict__ s_rec,
    const int* __restrict__ off, const int* __restrict__ cnt,
    const float* __restrict__ feat, const float* __restrict__ Wrw,
    const float* __restrict__ brw, const float* __restrict__ br,
    float* __restrict__ y) {
  int wave = threadIdx.x >> 6, lane = threadIdx.x & 63;
  int n = blockIdx.x * 4 + wave;
  if (n >= NN) return;

  // ---- inline rel_w softmax (all lanes end with rwv[0..3]) ----
  float rwv[4];
  {
    float2 f = reinterpret_cast<const float2*>(feat + (size_t)n * DD)[lane];
    float4 w0 = reinterpret_cast<const float4*>(Wrw)[2 * lane];
    float4 w1 = reinterpret_cast<const float4*>(Wrw)[2 * lane + 1];
    float a0 = f.x * w0.x + f.y * w1.x;
    float a1 = f.x * w0.y + f.y * w1.y;
    float a2 = f.x * w0.z + f.y * w1.z;
    float a3 = f.x * w0.w + f.y * w1.w;
    for (int o = 32; o; o >>= 1) {
      a0 += __shfl_xor(a0, o);
      a1 += __shfl_xor(a1, o);
      a2 += __shfl_xor(a2, o);
      a3 += __shfl_xor(a3, o);
    }
    a0 += brw[0]; a1 += brw[1]; a2 += brw[2]; a3 += brw[3];
    float m = fmaxf(fmaxf(a0, a1), fmaxf(a2, a3));
    float e0 = __expf(a0 - m), e1 = __expf(a1 - m);
    float e2 = __expf(a2 - m), e3 = __expf(a3 - m);
    float inv = 1.f / (e0 + e1 + e2 + e3);
    rwv[0] = e0 * inv; rwv[1] = e1 * inv; rwv[2] = e2 * inv; rwv[3] = e3 * inv;
  }

  float2 acc = make_float2(0.f, 0.f);
#pragma unroll
  for (int r = 0; r < NR; ++r) {
    int seg = r * NN + n;
    int start = off[seg], deg = cnt[seg];
    const __half2* mbase =
        reinterpret_cast<const __half2*>(M + (size_t)r * NN * DD);
    float2 pacc = make_float2(0.f, 0.f);
    float sw = 0.f;
    for (int i = 0; i < deg; i += 8) {
      int nb = deg - i;
      nb = nb > 8 ? 8 : nb;
      long long rr = 0;
      if (lane < nb)
        rr = __builtin_nontemporal_load(
            reinterpret_cast<const long long*>(s_rec + start + i + lane));
      int src_l = (int)(unsigned int)rr;
      float w_l = __uint_as_float((unsigned int)((unsigned long long)rr >> 32));
      if (nb == 8) {
#pragma unroll
        for (int j = 0; j < 8; ++j) {
          int s = __shfl(src_l, j);
          float w = __shfl(w_l, j);
          float2 mf = __half22float2(mbase[(size_t)s * 64 + lane]);
          pacc.x += w * mf.x;
          pacc.y += w * mf.y;
          sw += w;
        }
      } else {
        for (int j = 0; j < nb; ++j) {
          int s = __shfl(src_l, j);
          float w = __shfl(w_l, j);
          float2 mf = __half22float2(mbase[(size_t)s * 64 + lane]);
          pacc.x += w * mf.x;
          pacc.y += w * mf.y;
          sw += w;
        }
      }
    }
    float2 bv = reinterpret_cast<const float2*>(br + (size_t)r * DD)[lane];
    float rw = rwv[r];
    acc.x += rw * (pacc.x + sw * bv.x);
    acc.y += rw * (pacc.y + sw * bv.y);
  }
  reinterpret_cast<float2*>(y + (size_t)n * DD)[lane] = acc;
}

// ---------------------------------------------------------------------------
// gate: out = sigmoid(out @ Wg + bg) * out, in place. 128 nodes/block.
// ---------------------------------------------------------------------------
__global__ __launch_bounds__(256) void gate_kernel(
    float* __restrict__ out, const float* __restrict__ Wg,
    const float* __restrict__ bg) {
  __shared__ float wlds[DD * DD];
  __shared__ float clds[8][DD];
  for (int i = threadIdx.x; i < DD * DD / 4; i += 256)
    reinterpret_cast<float4*>(wlds)[i] = reinterpret_cast<const float4*>(Wg)[i];
  int dgrp = threadIdx.x & 31, nl = threadIdx.x >> 5;
  float4 bv = reinterpret_cast<const float4*>(bg)[dgrp];
  int nbase = blockIdx.x * 128;
  for (int s = 0; s < 16; ++s) {
    int n0 = nbase + s * 8;
    __syncthreads();
    {
      int n = n0 + nl;
      float4 cv = make_float4(0.f, 0.f, 0.f, 0.f);
      if (n < NN) cv = reinterpret_cast<const float4*>(out + (size_t)n * DD)[dgrp];
      reinterpret_cast<float4*>(&clds[nl][0])[dgrp] = cv;
    }
    __syncthreads();
    int n = n0 + nl;
    float4 acc = bv;
#pragma unroll 8
    for (int k = 0; k < DD; ++k) {
      float c = clds[nl][k];
      float4 wv = reinterpret_cast<const float4*>(&wlds[k * DD])[dgrp];
      acc.x += c * wv.x; acc.y += c * wv.y;
      acc.z += c * wv.z; acc.w += c * wv.w;
    }
    if (n < NN) {
      float4 cv = reinterpret_cast<float4*>(&clds[nl][0])[dgrp];
      float4 res;
      res.x = cv.x / (1.f + __expf(-acc.x));
      res.y = cv.y / (1.f + __expf(-acc.y));
      res.z = cv.z / (1.f + __expf(-acc.z));
      res.w = cv.w / (1.f + __expf(-acc.w));
      reinterpret_cast<float4*>(out + (size_t)n * DD)[dgrp] = res;
    }
  }
}

// ---------------------------------------------------------------------------
extern "C" void kernel_launch(void* const* d_in, const int* in_sizes, int n_in,
                              void* d_out, int out_size, void* d_ws,
                              size_t ws_size, hipStream_t stream) {
  const float* feat = (const float*)d_in[0];
  const int* eidx   = (const int*)d_in[1];   // [4][2][800000] int32
  const float* ew   = (const float*)d_in[2];
  const float* Wr   = (const float*)d_in[3];
  const float* br   = (const float*)d_in[4];
  const float* Wrw  = (const float*)d_in[5];
  const float* brw  = (const float*)d_in[6];
  const float* Wg   = (const float*)d_in[7];
  const float* bg   = (const float*)d_in[8];
  float* out = (float*)d_out;

  // ws layout (~79 MB): s_rec | cnt | off | offrun | part | M
  char* p = (char*)d_ws;
  int2*   s_rec  = (int2*)p;   p += (size_t)NR * NE * 8;       // 25.6 MB
  int*    cnt    = (int*)p;    p += (size_t)NSEG * 4;
  int*    off    = (int*)p;    p += (size_t)NSEG * 4;
  int*    offrun = (int*)p;    p += (size_t)NSEG * 4;
  int*    part   = (int*)p;    p += 4096;
  __half* M      = (__half*)p; p += (size_t)NR * NN * DD * 2;  // 51.2 MB

  hipMemsetAsync(cnt, 0, (size_t)NSEG * 4, stream);

  count_kernel<<<NXCD * CBLK, 256, 0, stream>>>(eidx, cnt);
  scan_local<<<NCHUNK, 256, 0, stream>>>(cnt, off, part);
  scan_partials<<<1, 256, 0, stream>>>(part);
  scan_add<<<NCHUNK, 256, 0, stream>>>(off, part, offrun);
  place_kernel<<<NXCD * CBLK, 256, 0, stream>>>(eidx, ew, offrun, s_rec);
  m_kernel<<<dim3((NN + 127) / 128, NR), 256, 0, stream>>>(feat, Wr, M);
  gather_y<<<(NN + 3) / 4, 256, 0, stream>>>(M, s_rec, off, cnt, feat, Wrw,
                                             brw, br, out);
  gate_kernel<<<(NN + 127) / 128, 256, 0, stream>>>(out, Wg, bg);
}

// Round 10
// 736.458 us; speedup vs baseline: 2.4452x; 1.1254x over previous
//
#include <hip/hip_runtime.h>
#include <hip/hip_fp16.h>

#define NN 50000
#define NR 4
#define NE 800000
#define DD 128
#define NSEG (NR * NN)                       // 200000 segments
#define SCHUNK 1024
#define NCHUNK ((NSEG + SCHUNK - 1) / SCHUNK)  // 196

// XCD slicing for count/place: 8 dst-slices, block bid&7 owns slice bid&7.
#define NXCD 8
#define DSLICE (NN / NXCD)      // 6250
#define CBLK 1563               // virtual blocks per slice; 8*1563 = 12504

// ---------------------------------------------------------------------------
// count (XCD-sliced): cnt[r*NN + dst]++ over all 3.2M edges
// ---------------------------------------------------------------------------
__global__ __launch_bounds__(256) void count_kernel(
    const int* __restrict__ eidx, int* __restrict__ cnt) {
  int xcd = blockIdx.x & (NXCD - 1);
  int vb = blockIdx.x >> 3;
  int lo = xcd * DSLICE, hi = lo + DSLICE;
  for (int idx = vb * 256 + threadIdx.x; idx < NR * NE; idx += CBLK * 256) {
    int r = idx / NE, e = idx - r * NE;
    int dst = eidx[(size_t)r * 2 * NE + NE + e];
    if (dst >= lo && dst < hi) atomicAdd(&cnt[r * NN + dst], 1);
  }
}

// ---------------------------------------------------------------------------
// 3-kernel exclusive scan over cnt[NSEG] -> off[NSEG]; off_run = copy
// ---------------------------------------------------------------------------
__global__ __launch_bounds__(256) void scan_local(
    const int* __restrict__ cnt, int* __restrict__ off,
    int* __restrict__ partial) {
  __shared__ int lds[256];
  int base = blockIdx.x * SCHUNK, t = threadIdx.x;
  int v[4], s = 0;
#pragma unroll
  for (int j = 0; j < 4; ++j) {
    int i = base + t * 4 + j;
    v[j] = (i < NSEG) ? cnt[i] : 0;
    s += v[j];
  }
  lds[t] = s;
  __syncthreads();
  for (int d = 1; d < 256; d <<= 1) {
    int x = (t >= d) ? lds[t - d] : 0;
    __syncthreads();
    lds[t] += x;
    __syncthreads();
  }
  int excl = (t == 0) ? 0 : lds[t - 1];
  if (t == 255) partial[blockIdx.x] = lds[255];
#pragma unroll
  for (int j = 0; j < 4; ++j) {
    int i = base + t * 4 + j;
    if (i < NSEG) off[i] = excl;
    excl += v[j];
  }
}

__global__ __launch_bounds__(256) void scan_partials(int* __restrict__ partial) {
  __shared__ int lds[256];
  int t = threadIdx.x;
  int v = (t < NCHUNK) ? partial[t] : 0;
  lds[t] = v;
  __syncthreads();
  for (int d = 1; d < 256; d <<= 1) {
    int x = (t >= d) ? lds[t - d] : 0;
    __syncthreads();
    lds[t] += x;
    __syncthreads();
  }
  int excl = (t == 0) ? 0 : lds[t - 1];
  if (t < NCHUNK) partial[t] = excl;
}

__global__ __launch_bounds__(256) void scan_add(
    int* __restrict__ off, const int* __restrict__ partial,
    int* __restrict__ off_run) {
  int base = blockIdx.x * SCHUNK;
  int add = partial[blockIdx.x];
  for (int j = threadIdx.x; j < SCHUNK; j += 256) {
    int i = base + j;
    if (i < NSEG) {
      int o = off[i] + add;
      off[i] = o;
      off_run[i] = o;
    }
  }
}

// ---------------------------------------------------------------------------
// place (XCD-sliced): s_rec[pos] = (src,w), pos = off_run[seg]++.
// ---------------------------------------------------------------------------
__global__ __launch_bounds__(256) void place_kernel(
    const int* __restrict__ eidx, const float* __restrict__ ew,
    int* __restrict__ off_run, int2* __restrict__ s_rec) {
  int xcd = blockIdx.x & (NXCD - 1);
  int vb = blockIdx.x >> 3;
  int lo = xcd * DSLICE, hi = lo + DSLICE;
  for (int idx = vb * 256 + threadIdx.x; idx < NR * NE; idx += CBLK * 256) {
    int r = idx / NE, e = idx - r * NE;
    int dst = eidx[(size_t)r * 2 * NE + NE + e];
    if (dst >= lo && dst < hi) {
      int src = eidx[(size_t)r * 2 * NE + e];
      float w = ew[(size_t)r * NE + e];
      int pos = atomicAdd(&off_run[r * NN + dst], 1);
      long long rec =
          (long long)(unsigned int)src | ((long long)__float_as_uint(w) << 32);
      __builtin_nontemporal_store(rec,
                                  reinterpret_cast<long long*>(s_rec + pos));
    }
  }
}

// ---------------------------------------------------------------------------
// m_kernel: M_r = F @ Wr[r] in fp16. blockIdx.y = r. 128 nodes/block.
// ---------------------------------------------------------------------------
__global__ __launch_bounds__(256) void m_kernel(
    const float* __restrict__ feat, const float* __restrict__ Wr,
    __half* __restrict__ M) {
  __shared__ float wlds[DD * DD];   // 64 KB
  __shared__ float flds[8][DD];     // 4 KB
  int r = blockIdx.y;
  const float* W = Wr + (size_t)r * DD * DD;
  for (int i = threadIdx.x; i < DD * DD / 4; i += 256)
    reinterpret_cast<float4*>(wlds)[i] = reinterpret_cast<const float4*>(W)[i];
  int dgrp = threadIdx.x & 31, nl = threadIdx.x >> 5;
  int nbase = blockIdx.x * 128;
  for (int s = 0; s < 16; ++s) {
    int n0 = nbase + s * 8;
    __syncthreads();
    {
      int n = n0 + nl;
      float4 fv = make_float4(0.f, 0.f, 0.f, 0.f);
      if (n < NN) fv = reinterpret_cast<const float4*>(feat + (size_t)n * DD)[dgrp];
      reinterpret_cast<float4*>(&flds[nl][0])[dgrp] = fv;
    }
    __syncthreads();
    int n = n0 + nl;
    float4 acc = make_float4(0.f, 0.f, 0.f, 0.f);
#pragma unroll 8
    for (int k = 0; k < DD; ++k) {
      float f = flds[nl][k];
      float4 wv = reinterpret_cast<const float4*>(&wlds[k * DD])[dgrp];
      acc.x += f * wv.x; acc.y += f * wv.y;
      acc.z += f * wv.z; acc.w += f * wv.w;
    }
    if (n < NN) {
      __half2 h01 = __floats2half2_rn(acc.x, acc.y);
      __half2 h23 = __floats2half2_rn(acc.z, acc.w);
      __half2* mp = reinterpret_cast<__half2*>(
          M + ((size_t)r * NN + n) * DD + 4 * dgrp);
      mp[0] = h01;
      mp[1] = h23;
    }
  }
}

// ---------------------------------------------------------------------------
// gather_y: one wave per node, zero LDS, high-ILP.
// 16-wide ZERO-PADDED batches (w=0 padding contributes nothing -> fully
// unrolled inner loop, 16 independent M loads in flight), cross-relation
// upfront preload (lane l holds slot l&15 of relation l>>4), and
// one-batch-ahead record prefetch. Inline rel_w softmax.
// ---------------------------------------------------------------------------
__global__ __launch_bounds__(256) void gather_y(
    const __half* __restrict__ M, const int2* __restrict__ s_rec,
    const int* __restrict__ off, const int* __restrict__ cnt,
    const float* __restrict__ feat, const float* __restrict__ Wrw,
    const float* __restrict__ brw, const float* __restrict__ br,
    float* __restrict__ y) {
  int wave = threadIdx.x >> 6, lane = threadIdx.x & 63;
  int n = blockIdx.x * 4 + wave;
  if (n >= NN) return;

  // ---- per-lane segment metadata: lane l -> relation l>>4, slot l&15 ----
  int l_r = lane >> 4, l_j = lane & 15;
  int l_seg = l_r * NN + n;
  int l_start = off[l_seg];
  int l_deg = cnt[l_seg];
  // upfront preload of batch 0 of all 4 relations
  int pre_s = 0;
  float pre_w = 0.f;
  if (l_j < l_deg) {
    long long rr = __builtin_nontemporal_load(
        reinterpret_cast<const long long*>(s_rec + l_start + l_j));
    pre_s = (int)(unsigned int)rr;
    pre_w = __uint_as_float((unsigned int)((unsigned long long)rr >> 32));
  }

  // ---- inline rel_w softmax (all lanes end with rwv[0..3]) ----
  float rwv[4];
  {
    float2 f = reinterpret_cast<const float2*>(feat + (size_t)n * DD)[lane];
    float4 w0 = reinterpret_cast<const float4*>(Wrw)[2 * lane];
    float4 w1 = reinterpret_cast<const float4*>(Wrw)[2 * lane + 1];
    float a0 = f.x * w0.x + f.y * w1.x;
    float a1 = f.x * w0.y + f.y * w1.y;
    float a2 = f.x * w0.z + f.y * w1.z;
    float a3 = f.x * w0.w + f.y * w1.w;
    for (int o = 32; o; o >>= 1) {
      a0 += __shfl_xor(a0, o);
      a1 += __shfl_xor(a1, o);
      a2 += __shfl_xor(a2, o);
      a3 += __shfl_xor(a3, o);
    }
    a0 += brw[0]; a1 += brw[1]; a2 += brw[2]; a3 += brw[3];
    float m = fmaxf(fmaxf(a0, a1), fmaxf(a2, a3));
    float e0 = __expf(a0 - m), e1 = __expf(a1 - m);
    float e2 = __expf(a2 - m), e3 = __expf(a3 - m);
    float inv = 1.f / (e0 + e1 + e2 + e3);
    rwv[0] = e0 * inv; rwv[1] = e1 * inv; rwv[2] = e2 * inv; rwv[3] = e3 * inv;
  }

  float2 acc = make_float2(0.f, 0.f);
#pragma unroll
  for (int r = 0; r < NR; ++r) {
    int start = __shfl(l_start, r << 4);
    int deg = __shfl(l_deg, r << 4);
    const __half2* mbase =
        reinterpret_cast<const __half2*>(M + (size_t)r * NN * DD);
    float2 pacc = make_float2(0.f, 0.f);
    float sw = 0.f;
    int nbat = (deg + 15) >> 4;
    int cur_s = pre_s;      // batch 0 lives in lanes [r*16, r*16+16)
    float cur_w = pre_w;
    int sb = r << 4;
    for (int b = 0; b < nbat; ++b) {
      // prefetch next batch into lanes 0..15 (zero-padded)
      int nxt_s = 0;
      float nxt_w = 0.f;
      int nbase = (b + 1) << 4;
      if (nbase < deg && lane < 16) {
        int idx2 = nbase + lane;
        if (idx2 < deg) {
          long long rr = __builtin_nontemporal_load(
              reinterpret_cast<const long long*>(s_rec + start + idx2));
          nxt_s = (int)(unsigned int)rr;
          nxt_w = __uint_as_float((unsigned int)((unsigned long long)rr >> 32));
        }
      }
#pragma unroll
      for (int j = 0; j < 16; ++j) {
        int s = __shfl(cur_s, sb + j);
        float w = __shfl(cur_w, sb + j);
        float2 mf = __half22float2(mbase[(size_t)s * 64 + lane]);
        pacc.x += w * mf.x;
        pacc.y += w * mf.y;
        sw += w;
      }
      cur_s = nxt_s;
      cur_w = nxt_w;
      sb = 0;
    }
    float2 bv = reinterpret_cast<const float2*>(br + (size_t)r * DD)[lane];
    float rw = rwv[r];
    acc.x += rw * (pacc.x + sw * bv.x);
    acc.y += rw * (pacc.y + sw * bv.y);
  }
  reinterpret_cast<float2*>(y + (size_t)n * DD)[lane] = acc;
}

// ---------------------------------------------------------------------------
// gate: out = sigmoid(out @ Wg + bg) * out, in place. 128 nodes/block.
// ---------------------------------------------------------------------------
__global__ __launch_bounds__(256) void gate_kernel(
    float* __restrict__ out, const float* __restrict__ Wg,
    const float* __restrict__ bg) {
  __shared__ float wlds[DD * DD];
  __shared__ float clds[8][DD];
  for (int i = threadIdx.x; i < DD * DD / 4; i += 256)
    reinterpret_cast<float4*>(wlds)[i] = reinterpret_cast<const float4*>(Wg)[i];
  int dgrp = threadIdx.x & 31, nl = threadIdx.x >> 5;
  float4 bv = reinterpret_cast<const float4*>(bg)[dgrp];
  int nbase = blockIdx.x * 128;
  for (int s = 0; s < 16; ++s) {
    int n0 = nbase + s * 8;
    __syncthreads();
    {
      int n = n0 + nl;
      float4 cv = make_float4(0.f, 0.f, 0.f, 0.f);
      if (n < NN) cv = reinterpret_cast<const float4*>(out + (size_t)n * DD)[dgrp];
      reinterpret_cast<float4*>(&clds[nl][0])[dgrp] = cv;
    }
    __syncthreads();
    int n = n0 + nl;
    float4 acc = bv;
#pragma unroll 8
    for (int k = 0; k < DD; ++k) {
      float c = clds[nl][k];
      float4 wv = reinterpret_cast<const float4*>(&wlds[k * DD])[dgrp];
      acc.x += c * wv.x; acc.y += c * wv.y;
      acc.z += c * wv.z; acc.w += c * wv.w;
    }
    if (n < NN) {
      float4 cv = reinterpret_cast<float4*>(&clds[nl][0])[dgrp];
      float4 res;
      res.x = cv.x / (1.f + __expf(-acc.x));
      res.y = cv.y / (1.f + __expf(-acc.y));
      res.z = cv.z / (1.f + __expf(-acc.z));
      res.w = cv.w / (1.f + __expf(-acc.w));
      reinterpret_cast<float4*>(out + (size_t)n * DD)[dgrp] = res;
    }
  }
}

// ---------------------------------------------------------------------------
extern "C" void kernel_launch(void* const* d_in, const int* in_sizes, int n_in,
                              void* d_out, int out_size, void* d_ws,
                              size_t ws_size, hipStream_t stream) {
  const float* feat = (const float*)d_in[0];
  const int* eidx   = (const int*)d_in[1];   // [4][2][800000] int32
  const float* ew   = (const float*)d_in[2];
  const float* Wr   = (const float*)d_in[3];
  const float* br   = (const float*)d_in[4];
  const float* Wrw  = (const float*)d_in[5];
  const float* brw  = (const float*)d_in[6];
  const float* Wg   = (const float*)d_in[7];
  const float* bg   = (const float*)d_in[8];
  float* out = (float*)d_out;

  // ws layout (~79 MB): s_rec | cnt | off | offrun | part | M
  char* p = (char*)d_ws;
  int2*   s_rec  = (int2*)p;   p += (size_t)NR * NE * 8;       // 25.6 MB
  int*    cnt    = (int*)p;    p += (size_t)NSEG * 4;
  int*    off    = (int*)p;    p += (size_t)NSEG * 4;
  int*    offrun = (int*)p;    p += (size_t)NSEG * 4;
  int*    part   = (int*)p;    p += 4096;
  __half* M      = (__half*)p; p += (size_t)NR * NN * DD * 2;  // 51.2 MB

  hipMemsetAsync(cnt, 0, (size_t)NSEG * 4, stream);

  count_kernel<<<NXCD * CBLK, 256, 0, stream>>>(eidx, cnt);
  scan_local<<<NCHUNK, 256, 0, stream>>>(cnt, off, part);
  scan_partials<<<1, 256, 0, stream>>>(part);
  scan_add<<<NCHUNK, 256, 0, stream>>>(off, part, offrun);
  place_kernel<<<NXCD * CBLK, 256, 0, stream>>>(eidx, ew, offrun, s_rec);
  m_kernel<<<dim3((NN + 127) / 128, NR), 256, 0, stream>>>(feat, Wr, M);
  gather_y<<<(NN + 3) / 4, 256, 0, stream>>>(M, s_rec, off, cnt, feat, Wrw,
                                             brw, br, out);
  gate_kernel<<<(NN + 127) / 128, 256, 0, stream>>>(out, Wg, bg);
}

// Round 11
// 603.751 us; speedup vs baseline: 2.9826x; 1.2198x over previous
//
#include <hip/hip_runtime.h>
#include <hip/hip_fp16.h>

#define NN 50000
#define NR 4
#define NE 800000
#define DD 128
#define NSEG (NR * NN)                       // 200000 segments
#define SCHUNK 1024
#define NCHUNK ((NSEG + SCHUNK - 1) / SCHUNK)  // 196

// XCD slicing for count/place: 8 dst-slices, block bid&7 owns slice bid&7.
#define NXCD 8
#define DSLICE (NN / NXCD)      // 6250
#define CBLK 1563               // virtual blocks per slice; 8*1563 = 12504

typedef _Float16 f16x8 __attribute__((ext_vector_type(8)));
typedef float f32x4 __attribute__((ext_vector_type(4)));

// ---------------------------------------------------------------------------
// count (XCD-sliced): cnt[r*NN + dst]++ over all 3.2M edges
// ---------------------------------------------------------------------------
__global__ __launch_bounds__(256) void count_kernel(
    const int* __restrict__ eidx, int* __restrict__ cnt) {
  int xcd = blockIdx.x & (NXCD - 1);
  int vb = blockIdx.x >> 3;
  int lo = xcd * DSLICE, hi = lo + DSLICE;
  for (int idx = vb * 256 + threadIdx.x; idx < NR * NE; idx += CBLK * 256) {
    int r = idx / NE, e = idx - r * NE;
    int dst = eidx[(size_t)r * 2 * NE + NE + e];
    if (dst >= lo && dst < hi) atomicAdd(&cnt[r * NN + dst], 1);
  }
}

// ---------------------------------------------------------------------------
// 3-kernel exclusive scan over cnt[NSEG] -> off[NSEG]; off_run = copy
// ---------------------------------------------------------------------------
__global__ __launch_bounds__(256) void scan_local(
    const int* __restrict__ cnt, int* __restrict__ off,
    int* __restrict__ partial) {
  __shared__ int lds[256];
  int base = blockIdx.x * SCHUNK, t = threadIdx.x;
  int v[4], s = 0;
#pragma unroll
  for (int j = 0; j < 4; ++j) {
    int i = base + t * 4 + j;
    v[j] = (i < NSEG) ? cnt[i] : 0;
    s += v[j];
  }
  lds[t] = s;
  __syncthreads();
  for (int d = 1; d < 256; d <<= 1) {
    int x = (t >= d) ? lds[t - d] : 0;
    __syncthreads();
    lds[t] += x;
    __syncthreads();
  }
  int excl = (t == 0) ? 0 : lds[t - 1];
  if (t == 255) partial[blockIdx.x] = lds[255];
#pragma unroll
  for (int j = 0; j < 4; ++j) {
    int i = base + t * 4 + j;
    if (i < NSEG) off[i] = excl;
    excl += v[j];
  }
}

__global__ __launch_bounds__(256) void scan_partials(int* __restrict__ partial) {
  __shared__ int lds[256];
  int t = threadIdx.x;
  int v = (t < NCHUNK) ? partial[t] : 0;
  lds[t] = v;
  __syncthreads();
  for (int d = 1; d < 256; d <<= 1) {
    int x = (t >= d) ? lds[t - d] : 0;
    __syncthreads();
    lds[t] += x;
    __syncthreads();
  }
  int excl = (t == 0) ? 0 : lds[t - 1];
  if (t < NCHUNK) partial[t] = excl;
}

__global__ __launch_bounds__(256) void scan_add(
    int* __restrict__ off, const int* __restrict__ partial,
    int* __restrict__ off_run) {
  int base = blockIdx.x * SCHUNK;
  int add = partial[blockIdx.x];
  for (int j = threadIdx.x; j < SCHUNK; j += 256) {
    int i = base + j;
    if (i < NSEG) {
      int o = off[i] + add;
      off[i] = o;
      off_run[i] = o;
    }
  }
}

// ---------------------------------------------------------------------------
// place (XCD-sliced): s_rec[pos] = (src,w), pos = off_run[seg]++.
// ---------------------------------------------------------------------------
__global__ __launch_bounds__(256) void place_kernel(
    const int* __restrict__ eidx, const float* __restrict__ ew,
    int* __restrict__ off_run, int2* __restrict__ s_rec) {
  int xcd = blockIdx.x & (NXCD - 1);
  int vb = blockIdx.x >> 3;
  int lo = xcd * DSLICE, hi = lo + DSLICE;
  for (int idx = vb * 256 + threadIdx.x; idx < NR * NE; idx += CBLK * 256) {
    int r = idx / NE, e = idx - r * NE;
    int dst = eidx[(size_t)r * 2 * NE + NE + e];
    if (dst >= lo && dst < hi) {
      int src = eidx[(size_t)r * 2 * NE + e];
      float w = ew[(size_t)r * NE + e];
      int pos = atomicAdd(&off_run[r * NN + dst], 1);
      long long rec =
          (long long)(unsigned int)src | ((long long)__float_as_uint(w) << 32);
      __builtin_nontemporal_store(rec,
                                  reinterpret_cast<long long*>(s_rec + pos));
    }
  }
}

// ---------------------------------------------------------------------------
// m_kernel (MFMA): M_r = F @ Wr[r] in fp16. blockIdx.y = r.
// Block = 4 waves x 16 nodes = 64 nodes. Wt[col][k] f16 in 32KB LDS with
// T2 XOR swizzle (byte ^= (col&7)<<4) so B-frag ds_read_b128 is ~conflict-
// free. A-frag from global F (8 consecutive f32 -> cvt). Per wave:
// 4 k-tiles x 8 col-tiles = 32 x mfma_f32_16x16x32_f16.
// Layouts (m89-verified convention): A[row=l&15][k=8*(l>>4)+i],
// B[k=8*(l>>4)+i][col=l&15], D[row=4*(l>>4)+j][col=l&15].
// ---------------------------------------------------------------------------
__global__ __launch_bounds__(256) void m_kernel(
    const float* __restrict__ feat, const float* __restrict__ Wr,
    __half* __restrict__ M) {
  __shared__ __half wt[DD * DD];   // 32 KB, Wt[col][k] swizzled
  int r = blockIdx.y;
  const float* W = Wr + (size_t)r * DD * DD;
  char* wtb = reinterpret_cast<char*>(wt);
  for (int i = threadIdx.x; i < DD * DD; i += 256) {
    int k = i >> 7, c = i & 127;   // W[k][c], consecutive i -> coalesced read
    int bo = (c * 256 + k * 2) ^ ((c & 7) << 4);
    *reinterpret_cast<_Float16*>(wtb + bo) = (_Float16)W[i];
  }
  __syncthreads();

  int wv = threadIdx.x >> 6, l = threadIdx.x & 63;
  int n0 = blockIdx.x * 64 + wv * 16;
  int arow = n0 + (l & 15);
  int kgrp = (l >> 4) * 8;
  const float* fr = feat + (size_t)(arow < NN ? arow : 0) * DD;

  f32x4 acc[8] = {};
  for (int k0 = 0; k0 < DD; k0 += 32) {
    float4 fa = *reinterpret_cast<const float4*>(fr + k0 + kgrp);
    float4 fb = *reinterpret_cast<const float4*>(fr + k0 + kgrp + 4);
    f16x8 a;
    a[0] = (_Float16)fa.x; a[1] = (_Float16)fa.y;
    a[2] = (_Float16)fa.z; a[3] = (_Float16)fa.w;
    a[4] = (_Float16)fb.x; a[5] = (_Float16)fb.y;
    a[6] = (_Float16)fb.z; a[7] = (_Float16)fb.w;
#pragma unroll
    for (int c = 0; c < 8; ++c) {
      int col = c * 16 + (l & 15);
      int bo = (col * 256 + (k0 + kgrp) * 2) ^ ((col & 7) << 4);
      f16x8 b = *reinterpret_cast<const f16x8*>(wtb + bo);
      acc[c] = __builtin_amdgcn_mfma_f32_16x16x32_f16(a, b, acc[c], 0, 0, 0);
    }
  }

  int rbase = n0 + 4 * (l >> 4);
  __half* Mr = M + (size_t)r * NN * DD;
#pragma unroll
  for (int c = 0; c < 8; ++c) {
    int col = c * 16 + (l & 15);
#pragma unroll
    for (int j = 0; j < 4; ++j) {
      int row = rbase + j;
      if (row < NN) Mr[(size_t)row * DD + col] = __float2half(acc[c][j]);
    }
  }
}

// ---------------------------------------------------------------------------
// gather_y: one wave per node, zero LDS, high-ILP (16-wide zero-padded
// batches, cross-relation upfront preload, one-batch-ahead prefetch).
// Inline rel_w softmax.
// ---------------------------------------------------------------------------
__global__ __launch_bounds__(256) void gather_y(
    const __half* __restrict__ M, const int2* __restrict__ s_rec,
    const int* __restrict__ off, const int* __restrict__ cnt,
    const float* __restrict__ feat, const float* __restrict__ Wrw,
    const float* __restrict__ brw, const float* __restrict__ br,
    float* __restrict__ y) {
  int wave = threadIdx.x >> 6, lane = threadIdx.x & 63;
  int n = blockIdx.x * 4 + wave;
  if (n >= NN) return;

  int l_r = lane >> 4, l_j = lane & 15;
  int l_seg = l_r * NN + n;
  int l_start = off[l_seg];
  int l_deg = cnt[l_seg];
  int pre_s = 0;
  float pre_w = 0.f;
  if (l_j < l_deg) {
    long long rr = __builtin_nontemporal_load(
        reinterpret_cast<const long long*>(s_rec + l_start + l_j));
    pre_s = (int)(unsigned int)rr;
    pre_w = __uint_as_float((unsigned int)((unsigned long long)rr >> 32));
  }

  float rwv[4];
  {
    float2 f = reinterpret_cast<const float2*>(feat + (size_t)n * DD)[lane];
    float4 w0 = reinterpret_cast<const float4*>(Wrw)[2 * lane];
    float4 w1 = reinterpret_cast<const float4*>(Wrw)[2 * lane + 1];
    float a0 = f.x * w0.x + f.y * w1.x;
    float a1 = f.x * w0.y + f.y * w1.y;
    float a2 = f.x * w0.z + f.y * w1.z;
    float a3 = f.x * w0.w + f.y * w1.w;
    for (int o = 32; o; o >>= 1) {
      a0 += __shfl_xor(a0, o);
      a1 += __shfl_xor(a1, o);
      a2 += __shfl_xor(a2, o);
      a3 += __shfl_xor(a3, o);
    }
    a0 += brw[0]; a1 += brw[1]; a2 += brw[2]; a3 += brw[3];
    float m = fmaxf(fmaxf(a0, a1), fmaxf(a2, a3));
    float e0 = __expf(a0 - m), e1 = __expf(a1 - m);
    float e2 = __expf(a2 - m), e3 = __expf(a3 - m);
    float inv = 1.f / (e0 + e1 + e2 + e3);
    rwv[0] = e0 * inv; rwv[1] = e1 * inv; rwv[2] = e2 * inv; rwv[3] = e3 * inv;
  }

  float2 acc = make_float2(0.f, 0.f);
#pragma unroll
  for (int r = 0; r < NR; ++r) {
    int start = __shfl(l_start, r << 4);
    int deg = __shfl(l_deg, r << 4);
    const __half2* mbase =
        reinterpret_cast<const __half2*>(M + (size_t)r * NN * DD);
    float2 pacc = make_float2(0.f, 0.f);
    float sw = 0.f;
    int nbat = (deg + 15) >> 4;
    int cur_s = pre_s;
    float cur_w = pre_w;
    int sb = r << 4;
    for (int b = 0; b < nbat; ++b) {
      int nxt_s = 0;
      float nxt_w = 0.f;
      int nbase = (b + 1) << 4;
      if (nbase < deg && lane < 16) {
        int idx2 = nbase + lane;
        if (idx2 < deg) {
          long long rr = __builtin_nontemporal_load(
              reinterpret_cast<const long long*>(s_rec + start + idx2));
          nxt_s = (int)(unsigned int)rr;
          nxt_w = __uint_as_float((unsigned int)((unsigned long long)rr >> 32));
        }
      }
#pragma unroll
      for (int j = 0; j < 16; ++j) {
        int s = __shfl(cur_s, sb + j);
        float w = __shfl(cur_w, sb + j);
        float2 mf = __half22float2(mbase[(size_t)s * 64 + lane]);
        pacc.x += w * mf.x;
        pacc.y += w * mf.y;
        sw += w;
      }
      cur_s = nxt_s;
      cur_w = nxt_w;
      sb = 0;
    }
    float2 bv = reinterpret_cast<const float2*>(br + (size_t)r * DD)[lane];
    float rw = rwv[r];
    acc.x += rw * (pacc.x + sw * bv.x);
    acc.y += rw * (pacc.y + sw * bv.y);
  }
  reinterpret_cast<float2*>(y + (size_t)n * DD)[lane] = acc;
}

// ---------------------------------------------------------------------------
// gate: out = sigmoid(out @ Wg + bg) * out, in place. 128 nodes/block.
// ---------------------------------------------------------------------------
__global__ __launch_bounds__(256) void gate_kernel(
    float* __restrict__ out, const float* __restrict__ Wg,
    const float* __restrict__ bg) {
  __shared__ float wlds[DD * DD];
  __shared__ float clds[8][DD];
  for (int i = threadIdx.x; i < DD * DD / 4; i += 256)
    reinterpret_cast<float4*>(wlds)[i] = reinterpret_cast<const float4*>(Wg)[i];
  int dgrp = threadIdx.x & 31, nl = threadIdx.x >> 5;
  float4 bv = reinterpret_cast<const float4*>(bg)[dgrp];
  int nbase = blockIdx.x * 128;
  for (int s = 0; s < 16; ++s) {
    int n0 = nbase + s * 8;
    __syncthreads();
    {
      int n = n0 + nl;
      float4 cv = make_float4(0.f, 0.f, 0.f, 0.f);
      if (n < NN) cv = reinterpret_cast<const float4*>(out + (size_t)n * DD)[dgrp];
      reinterpret_cast<float4*>(&clds[nl][0])[dgrp] = cv;
    }
    __syncthreads();
    int n = n0 + nl;
    float4 acc = bv;
#pragma unroll 8
    for (int k = 0; k < DD; ++k) {
      float c = clds[nl][k];
      float4 wv = reinterpret_cast<const float4*>(&wlds[k * DD])[dgrp];
      acc.x += c * wv.x; acc.y += c * wv.y;
      acc.z += c * wv.z; acc.w += c * wv.w;
    }
    if (n < NN) {
      float4 cv = reinterpret_cast<float4*>(&clds[nl][0])[dgrp];
      float4 res;
      res.x = cv.x / (1.f + __expf(-acc.x));
      res.y = cv.y / (1.f + __expf(-acc.y));
      res.z = cv.z / (1.f + __expf(-acc.z));
      res.w = cv.w / (1.f + __expf(-acc.w));
      reinterpret_cast<float4*>(out + (size_t)n * DD)[dgrp] = res;
    }
  }
}

// ---------------------------------------------------------------------------
extern "C" void kernel_launch(void* const* d_in, const int* in_sizes, int n_in,
                              void* d_out, int out_size, void* d_ws,
                              size_t ws_size, hipStream_t stream) {
  const float* feat = (const float*)d_in[0];
  const int* eidx   = (const int*)d_in[1];   // [4][2][800000] int32
  const float* ew   = (const float*)d_in[2];
  const float* Wr   = (const float*)d_in[3];
  const float* br   = (const float*)d_in[4];
  const float* Wrw  = (const float*)d_in[5];
  const float* brw  = (const float*)d_in[6];
  const float* Wg   = (const float*)d_in[7];
  const float* bg   = (const float*)d_in[8];
  float* out = (float*)d_out;

  // ws layout (~79 MB): s_rec | cnt | off | offrun | part | M
  char* p = (char*)d_ws;
  int2*   s_rec  = (int2*)p;   p += (size_t)NR * NE * 8;       // 25.6 MB
  int*    cnt    = (int*)p;    p += (size_t)NSEG * 4;
  int*    off    = (int*)p;    p += (size_t)NSEG * 4;
  int*    offrun = (int*)p;    p += (size_t)NSEG * 4;
  int*    part   = (int*)p;    p += 4096;
  __half* M      = (__half*)p; p += (size_t)NR * NN * DD * 2;  // 51.2 MB

  hipMemsetAsync(cnt, 0, (size_t)NSEG * 4, stream);

  count_kernel<<<NXCD * CBLK, 256, 0, stream>>>(eidx, cnt);
  scan_local<<<NCHUNK, 256, 0, stream>>>(cnt, off, part);
  scan_partials<<<1, 256, 0, stream>>>(part);
  scan_add<<<NCHUNK, 256, 0, stream>>>(off, part, offrun);
  place_kernel<<<NXCD * CBLK, 256, 0, stream>>>(eidx, ew, offrun, s_rec);
  m_kernel<<<dim3((NN + 63) / 64, NR), 256, 0, stream>>>(feat, Wr, M);
  gather_y<<<(NN + 3) / 4, 256, 0, stream>>>(M, s_rec, off, cnt, feat, Wrw,
                                             brw, br, out);
  gate_kernel<<<(NN + 127) / 128, 256, 0, stream>>>(out, Wg, bg);
}